// Round 7
// baseline (355.428 us; speedup 1.0000x reference)
//
#include <hip/hip_runtime.h>

#define N_TOT 10000
#define CLS_P 1000
#define NC 10
#define D 1024

#define TM 128            // block tile (i and j)
#define DELTA 1.35e-5f
#define INV_SCALE2 4.8828125e-4f   // 2 / 4096  (Xh stores 64*x; acc = 4096*dot)
#define ESC_LOC 256
#define KCHUNKS (D / 32)
#define NTILE ((N_TOT + TM - 1) / TM)   // 79
#define NACT ((NTILE * (NTILE + 1)) / 2)  // 3160 active (upper-tri) tiles
#define CHUNK (NACT / 8)                  // 395 (exact: 3160 = 8*395)

typedef _Float16 f16x8 __attribute__((ext_vector_type(8)));
typedef float f32x4 __attribute__((ext_vector_type(4)));
typedef float f32x16 __attribute__((ext_vector_type(16)));
typedef const __attribute__((address_space(1))) unsigned int* gptr_t;
typedef __attribute__((address_space(3))) unsigned int* lptr_t;

// ---------------- gather + fp16(64x) + fp64 norms + fused counts-zero ----------------
__global__ void prep_kernel(const float* __restrict__ feats, const int* __restrict__ ids,
                            unsigned short* __restrict__ Xh,
                            double* __restrict__ sqd, float* __restrict__ sqf,
                            int* __restrict__ counts) {
    int row = blockIdx.x;
    int id = ids[row];
    const float4* rp = (const float4*)(feats + (size_t)id * D);
    float4 v = rp[threadIdx.x];  // 256 threads * 4 = 1024
    float f[4] = {v.x, v.y, v.z, v.w};
    ushort4 hv;
    unsigned short* hp = &hv.x;
    double s = 0.0;
    #pragma unroll
    for (int e = 0; e < 4; e++) {
        s += (double)f[e] * f[e];
        union { _Float16 h; unsigned short u; } cv;
        cv.h = (_Float16)(f[e] * 64.0f);   // RNE; x64 avoids fp16 denormals
        hp[e] = cv.u;
    }
    *(ushort4*)(Xh + (size_t)row * D + threadIdx.x * 4) = hv;

    #pragma unroll
    for (int off = 32; off > 0; off >>= 1)
        s += __shfl_down(s, off, 64);
    __shared__ double wsum[4];
    int lane = threadIdx.x & 63, wv = threadIdx.x >> 6;
    if (lane == 0) wsum[wv] = s;
    __syncthreads();
    if (threadIdx.x == 0) {
        double t = wsum[0] + wsum[1] + wsum[2] + wsum[3];
        sqd[row] = t;
        sqf[row] = (float)t;
        counts[row] = 0;        // fused zero (stream-ordered before count_kernel)
    }
}

// ---------------- fp16 MFMA pairwise count (3-buf async, 32x32x16 MFMA, fused fp64 escalation) ----------------
// R6 structure (219 us verified: balanced XCD chunking + ring-3 + read-ahead)
// with 32x32x16 MFMA (ubench 2382-2495 TF vs 2075-2176 for 16x16x32; half the
// instruction count, identical LDS traffic/swizzle).  C/D layout (m74/m101):
// col=lane&31, row=(reg&3)+8*(reg>>2)+4*(lane>>5).
__launch_bounds__(256, 3)
__global__ void count_kernel(const unsigned short* __restrict__ Xh,
                             const float* __restrict__ sqf,
                             const double* __restrict__ sqd,
                             const float* __restrict__ feats,
                             const int* __restrict__ ids,
                             int* __restrict__ counts) {
    // ---- XCD chunk remap (3160 = 8*395 exactly -> bijective) ----
    const int hw = blockIdx.x;
    const int gid = (hw & 7) * CHUNK + (hw >> 3);

    // ---- balanced active-tile decode: band-major (8 i-tiles/band), j-fastest ----
    int it_t, jt_t;
    {
        int rem = gid, b = 0, h;
        while (true) {
            h = NTILE - b * 8; if (h > 8) h = 8;
            int cnt = (h * (h + 1)) / 2 + h * (NTILE - b * 8 - h);
            if (rem < cnt) break;
            rem -= cnt; b++;
        }
        const int base = b * 8;
        const int T = (h * (h + 1)) / 2;
        if (rem < T) {
            // triangle head: jt = base+k has k+1 entries (it = base..base+k)
            int k = 0, a2 = 0;
            while (a2 + k + 1 <= rem) { a2 += k + 1; k++; }
            jt_t = base + k;
            it_t = base + (rem - a2);
        } else {
            // rectangle: only bands with h==8 reach here -> /8 is a shift
            int r2 = rem - T;
            jt_t = base + h + (r2 >> 3);
            it_t = base + (r2 & 7);
        }
    }
    const int ib = it_t * TM, jb = jt_t * TM;

    // skip tiles that are entirely same-class
    {
        int ci0 = ib / CLS_P, ci1 = (ib + TM - 1) / CLS_P;
        int cj0 = jb / CLS_P, cj1 = (jb + TM - 1) / CLS_P;
        if (ci0 == ci1 && cj0 == cj1 && ci0 == cj0) return;
    }

    // 3 buffers x (A 8KB + B 8KB) = 48 KB
    __shared__ unsigned short S[3 * 8192];
    __shared__ int cred_i[TM], cred_j[TM];
    __shared__ int esc_n;
    __shared__ int2 esc_buf[ESC_LOC];

    const int tid = threadIdx.x;
    const int lane = tid & 63, w = tid >> 6;
    const int wi = (w & 1) * 64, wj = (w >> 1) * 64;
    const int hh = lane >> 5;       // half-wave index (k-sub for frags / row+4h for C)
    const int l31 = lane & 31;

    if (tid == 0) esc_n = 0;

    // staging: waves 0,1 -> A (rows of ib); waves 2,3 -> B (rows of jb)
    const int warr = w >> 1;
    const int w01 = w & 1;
    const int rl0 = lane >> 2;      // 0..15 row within 16-row call group
    const int slot = lane & 3;      // dest k-slot
    const int q = (slot - rl0 - (rl0 >> 2)) & 3;   // source k-quarter (swizzle)
    const int rowbase = warr ? jb : ib;

    const unsigned short* src[4];
    #pragma unroll
    for (int b = 0; b < 4; b++) {
        int grow = rowbase + b * 32 + w01 * 16 + rl0;
        if (grow > N_TOT - 1) grow = N_TOT - 1;
        src[b] = Xh + (size_t)grow * D + q * 8;
    }

#define STAGE(KC_, BUFBASE_)                                                     \
    {                                                                            \
        _Pragma("unroll")                                                        \
        for (int b = 0; b < 4; b++) {                                            \
            __builtin_amdgcn_global_load_lds(                                    \
                (gptr_t)(src[b] + (KC_) * 32),                                   \
                (lptr_t)((BUFBASE_) + warr * 4096 + b * 1024 + w01 * 512),       \
                16, 0, 0);                                                       \
        }                                                                        \
    }

    // ---- hoisted frag LDS offsets (shorts); 32x32x16 layout:
    //      A-frag(rb,ks): row rA = wi+rb*32+l31, logical k-slot = 2*ks+hh,
    //      phys slot = (2*ks+hh + rA + (rA>>2)) & 3  (same rotation as staging) ----
    int offA[4], offB[4];   // index = rb*2+ks / cb*2+ks
    #pragma unroll
    for (int rb = 0; rb < 2; rb++)
        #pragma unroll
        for (int ks = 0; ks < 2; ks++) {
            int rA = wi + rb * 32 + l31;
            offA[rb * 2 + ks] = rA * 32 + ((2 * ks + hh + rA + (rA >> 2)) & 3) * 8;
            int rB = wj + rb * 32 + l31;
            offB[rb * 2 + ks] = 4096 + rB * 32 + ((2 * ks + hh + rB + (rB >> 2)) & 3) * 8;
        }

#define FRAGS_(AH, BH, BUFBASE_)                                                 \
    {                                                                            \
        _Pragma("unroll")                                                        \
        for (int t = 0; t < 4; t++) {                                            \
            AH[t] = *(const f16x8*)((BUFBASE_) + offA[t]);                       \
            BH[t] = *(const f16x8*)((BUFBASE_) + offB[t]);                       \
        }                                                                        \
    }

#define MFMA8_(AH, BH)                                                           \
    {                                                                            \
        _Pragma("unroll")                                                        \
        for (int ks = 0; ks < 2; ks++)                                           \
            _Pragma("unroll")                                                    \
            for (int rb = 0; rb < 2; rb++)                                       \
                _Pragma("unroll")                                                \
                for (int cb = 0; cb < 2; cb++)                                   \
                    acc[rb][cb] = __builtin_amdgcn_mfma_f32_32x32x16_f16(        \
                        AH[rb * 2 + ks], BH[cb * 2 + ks], acc[rb][cb], 0, 0, 0); \
    }

#define WAIT4_BAR asm volatile("s_waitcnt vmcnt(4)\ns_barrier" ::: "memory")
#define WAIT0_BAR asm volatile("s_waitcnt vmcnt(0)\ns_barrier" ::: "memory")

    f32x16 acc[2][2];
    #pragma unroll
    for (int e = 0; e < 16; e++) {
        acc[0][0][e] = 0.f; acc[0][1][e] = 0.f;
        acc[1][0][e] = 0.f; acc[1][1][e] = 0.f;
    }

    f16x8 ah0[4], bh0[4], ah1[4], bh1[4];   // two named frag sets (phase parity)

    unsigned short* p0 = S;                 // data kc   (cur, already in regs)
    unsigned short* p1 = S + 8192;          // data kc+1 (frags read this phase)
    unsigned short* p2 = S + 16384;         // free -> staging kc+2

    // prologue: stage kc0,kc1; retire kc0 (keep kc1 in flight); preload frags0
    STAGE(0, p0);
    STAGE(1, p1);
    WAIT4_BAR;
    FRAGS_(ah0, bh0, p0);

    for (int kc = 0; kc < KCHUNKS - 2; kc += 2) {
        // ---- phase m=kc (cur set0): stage kc+2, read-ahead frags kc+1 -> set1 ----
        STAGE(kc + 2, p2);
        WAIT4_BAR;                 // retire stage(kc+1) everywhere; gate p2 overwrite
        FRAGS_(ah1, bh1, p1);      // ds_reads overlap MFMA below
        MFMA8_(ah0, bh0);
        { unsigned short* t = p0; p0 = p1; p1 = p2; p2 = t; }

        // ---- phase m=kc+1 (cur set1): stage kc+3, read-ahead frags kc+2 -> set0 ----
        STAGE(kc + 3, p2);
        WAIT4_BAR;
        FRAGS_(ah0, bh0, p1);
        MFMA8_(ah1, bh1);
        { unsigned short* t = p0; p0 = p1; p1 = p2; p2 = t; }
    }
    // tail: phase 30 (cur set0), phase 31 (cur set1)
    WAIT0_BAR;                     // retire stage(31)
    FRAGS_(ah1, bh1, p1);
    MFMA8_(ah0, bh0);
    MFMA8_(ah1, bh1);

    // ---------------- epilogue: threshold + LDS-buffered escalate + symmetric reduce ----------------
    if (tid < TM) { cred_i[tid] = 0; cred_j[tid] = 0; }
    __syncthreads();

    const float thr_lo = 0.25f - DELTA;
    const float thr_hi = 0.25f + DELTA;
    const bool diag = (ib == jb);

    // j depends only on cb: j = jb + wj + cb*32 + l31
    float sqj2[2];
    int clsj2[2], jv2[2], jidx2[2];
    #pragma unroll
    for (int cb = 0; cb < 2; cb++) {
        int j = jb + wj + cb * 32 + l31;
        jidx2[cb] = j;
        jv2[cb] = (j < N_TOT);
        sqj2[cb] = jv2[cb] ? sqf[j] : 0.f;
        clsj2[cb] = j / CLS_P;
    }

    int cj2[2] = {0, 0};

    #pragma unroll
    for (int rb = 0; rb < 2; rb++) {
        #pragma unroll
        for (int reg = 0; reg < 16; reg++) {
            int irow = wi + rb * 32 + (reg & 3) + ((reg >> 2) << 3) + (hh << 2);
            int i = ib + irow;
            bool iv = (i < N_TOT);
            float sqi = iv ? sqf[i] : 0.f;
            int clsi = i / CLS_P;
            int ci = 0;
            #pragma unroll
            for (int cb = 0; cb < 2; cb++) {
                int j = jidx2[cb];
                bool ok = iv && jv2[cb] && (clsj2[cb] != clsi) && (!diag || j > i);
                float d2 = sqi + sqj2[cb] - acc[rb][cb][reg] * INV_SCALE2;
                bool in = ok && (d2 < thr_lo);
                bool esc = ok && !in && (d2 < thr_hi);
                ci += in ? 1 : 0;
                cj2[cb] += in ? 1 : 0;
                if (esc) {
                    int k = atomicAdd(&esc_n, 1);      // LDS atomic: fast
                    if (k < ESC_LOC) {
                        esc_buf[k] = make_int2(i, j);
                    } else {
                        // ~never (avg ~16/block, cap 256): exact inline scalar fp64 check
                        const float* xi = feats + (size_t)ids[i] * D;
                        const float* xj = feats + (size_t)ids[j] * D;
                        double s = 0.0;
                        for (int kk = 0; kk < D; kk++) s += (double)xi[kk] * xj[kk];
                        if (sqd[i] + sqd[j] - 2.0 * s < 0.25) {
                            atomicAdd(&counts[i], 1);
                            atomicAdd(&counts[j], 1);
                        }
                    }
                }
            }
            // reduce over the 32 j-lanes of this half-wave (i constant there)
            ci += __shfl_xor(ci, 1, 64);
            ci += __shfl_xor(ci, 2, 64);
            ci += __shfl_xor(ci, 4, 64);
            ci += __shfl_xor(ci, 8, 64);
            ci += __shfl_xor(ci, 16, 64);
            if (l31 == 0 && ci) atomicAdd(&cred_i[irow], ci);
        }
    }
    // j-credit: lane l and l+32 share j -> one cross-half shfl
    #pragma unroll
    for (int cb = 0; cb < 2; cb++) {
        int v = cj2[cb];
        v += __shfl_xor(v, 32, 64);
        if (hh == 0 && v) atomicAdd(&cred_j[wj + cb * 32 + l31], v);
    }
    __syncthreads();
    if (tid < TM) {
        int i = ib + tid;
        if (i < N_TOT && cred_i[tid]) atomicAdd(&counts[i], cred_i[tid]);
        int j = jb + tid;
        if (j < N_TOT && cred_j[tid]) atomicAdd(&counts[j], cred_j[tid]);
    }
    __syncthreads();   // esc_buf/esc_n visible to all waves

    // ---------------- fused fp64 escalation: 16 lanes/pair, 16 concurrent pairs ----------------
    int n = esc_n; if (n > ESC_LOC) n = ESC_LOC;
    const int sub = lane >> 4, l16 = lane & 15;
    for (int p = w * 4 + sub; p < n; p += 16) {
        int2 pr = esc_buf[p];
        const float* xi = feats + (size_t)ids[pr.x] * D;
        const float* xj = feats + (size_t)ids[pr.y] * D;
        double s = 0.0;
        int k0 = l16 * 64;
        #pragma unroll
        for (int k = 0; k < 64; k += 4) {
            float4 a = *(const float4*)(xi + k0 + k);
            float4 b = *(const float4*)(xj + k0 + k);
            s += (double)a.x * b.x + (double)a.y * b.y + (double)a.z * b.z + (double)a.w * b.w;
        }
        s += __shfl_xor(s, 1, 64);
        s += __shfl_xor(s, 2, 64);
        s += __shfl_xor(s, 4, 64);
        s += __shfl_xor(s, 8, 64);
        if (l16 == 0) {
            double d2 = sqd[pr.x] + sqd[pr.y] - 2.0 * s;
            if (d2 < 0.25) {
                atomicAdd(&counts[pr.x], 1);
                atomicAdd(&counts[pr.y], 1);
            }
        }
    }
}

// ---------------- stable-argsort selection (one thread per p) ----------------
__global__ void sel_kernel(const int* __restrict__ counts, const int* __restrict__ ids,
                           int* __restrict__ out_ids, int pcb) {
    int c = blockIdx.x;
    __shared__ int lc[CLS_P];
    for (int p = threadIdx.x; p < CLS_P; p += blockDim.x)
        lc[p] = counts[c * CLS_P + p];
    __syncthreads();
    int p = threadIdx.x;
    if (p < CLS_P) {
        int cp = lc[p];
        int rank = 0;
        for (int qq = 0; qq < CLS_P; qq++) {
            int cq = lc[qq];
            rank += (cq < cp) || (cq == cp && qq < p);
        }
        if (rank < pcb)
            out_ids[c * pcb + rank] = ids[c * CLS_P + p];
    }
}

extern "C" void kernel_launch(void* const* d_in, const int* in_sizes, int n_in,
                              void* d_out, int out_size, void* d_ws, size_t ws_size,
                              hipStream_t stream) {
    const float* feats = (const float*)d_in[0];
    const int* ids = (const int*)d_in[1];
    int budget = out_size - N_TOT;
    int pcb = budget / NC;  // 200
    int* out = (int*)d_out;
    int* counts_out = out + NC * pcb;

    char* ws = (char*)d_ws;
    const size_t XH_OFF = 0;
    const size_t SQD_OFF = XH_OFF + (size_t)N_TOT * D * 2;           // 20.48 MB
    const size_t SQF_OFF = SQD_OFF + (size_t)N_TOT * 8;

    unsigned short* Xh = (unsigned short*)(ws + XH_OFF);
    double* sqd = (double*)(ws + SQD_OFF);
    float* sqf = (float*)(ws + SQF_OFF);

    // counts zeroed inside prep; out_ids fully overwritten by sel (rank bijection)
    prep_kernel<<<N_TOT, 256, 0, stream>>>(feats, ids, Xh, sqd, sqf, counts_out);
    count_kernel<<<NACT, 256, 0, stream>>>(Xh, sqf, sqd, feats, ids, counts_out);
    sel_kernel<<<NC, 1024, 0, stream>>>(counts_out, ids, out, pcb);
}

// Round 8
// 328.067 us; speedup vs baseline: 1.0834x; 1.0834x over previous
//
#include <hip/hip_runtime.h>

#define N_TOT 10000
#define CLS_P 1000
#define NC 10
#define D 1024

#define TM 128            // block tile (i and j)
#define DELTA 1.35e-5f
#define INV_SCALE2 4.8828125e-4f   // 2 / 4096  (Xh stores 64*x; acc = 4096*dot)
#define ESC_LOC 256
#define KCHUNKS (D / 32)
#define NTILE ((N_TOT + TM - 1) / TM)   // 79
#define NACT ((NTILE * (NTILE + 1)) / 2)  // 3160 active (upper-tri) tiles
#define CHUNK (NACT / 8)                  // 395 (exact: 3160 = 8*395)

typedef _Float16 f16x8 __attribute__((ext_vector_type(8)));
typedef float f32x4 __attribute__((ext_vector_type(4)));
typedef const __attribute__((address_space(1))) unsigned int* gptr_t;
typedef __attribute__((address_space(3))) unsigned int* lptr_t;

// ---------------- gather + fp16(64x) + fp64 norms + fused counts-zero ----------------
__global__ void prep_kernel(const float* __restrict__ feats, const int* __restrict__ ids,
                            unsigned short* __restrict__ Xh,
                            double* __restrict__ sqd, float* __restrict__ sqf,
                            int* __restrict__ counts) {
    int row = blockIdx.x;
    int id = ids[row];
    const float4* rp = (const float4*)(feats + (size_t)id * D);
    float4 v = rp[threadIdx.x];  // 256 threads * 4 = 1024
    float f[4] = {v.x, v.y, v.z, v.w};
    ushort4 hv;
    unsigned short* hp = &hv.x;
    double s = 0.0;
    #pragma unroll
    for (int e = 0; e < 4; e++) {
        s += (double)f[e] * f[e];
        union { _Float16 h; unsigned short u; } cv;
        cv.h = (_Float16)(f[e] * 64.0f);   // RNE; x64 avoids fp16 denormals
        hp[e] = cv.u;
    }
    *(ushort4*)(Xh + (size_t)row * D + threadIdx.x * 4) = hv;

    #pragma unroll
    for (int off = 32; off > 0; off >>= 1)
        s += __shfl_down(s, off, 64);
    __shared__ double wsum[4];
    int lane = threadIdx.x & 63, wv = threadIdx.x >> 6;
    if (lane == 0) wsum[wv] = s;
    __syncthreads();
    if (threadIdx.x == 0) {
        double t = wsum[0] + wsum[1] + wsum[2] + wsum[3];
        sqd[row] = t;
        sqf[row] = (float)t;
        counts[row] = 0;        // fused zero (stream-ordered before count_kernel)
    }
}

// ---------------- fp16 MFMA pairwise count (3-buf async, frag read-ahead, fused fp64 escalation) ----------------
// FINAL (R6-verified, 219 us count / 326 us total): balanced active-tile XCD
// chunking (3160 = 8*395 upper-tri tiles, band-major j-fastest -> per-XCD
// L2-resident A-band, FETCH 452->224 MB, zero tail imbalance) + ring-3 LDS
// with counted vmcnt(4) and cross-chunk fragment read-ahead (16x16x32 MFMA,
// 16 independent MFMAs/cluster feeds the 3-wave/SIMD interleave).
// Bracketing measured this session: 8-phase/counted-vmcnt/sched_barrier
// schedules (R1-R3) worse at 1 block/CU; ring-2 4-block (R4, 37.9% occ) 250us;
// 32x32x16 shape (R7) 270us despite zero bank conflicts.
__launch_bounds__(256, 3)
__global__ void count_kernel(const unsigned short* __restrict__ Xh,
                             const float* __restrict__ sqf,
                             const double* __restrict__ sqd,
                             const float* __restrict__ feats,
                             const int* __restrict__ ids,
                             int* __restrict__ counts) {
    // ---- XCD chunk remap (3160 = 8*395 exactly -> bijective) ----
    const int hw = blockIdx.x;
    const int gid = (hw & 7) * CHUNK + (hw >> 3);

    // ---- balanced active-tile decode: band-major (8 i-tiles/band), j-fastest ----
    int it_t, jt_t;
    {
        int rem = gid, b = 0, h;
        while (true) {
            h = NTILE - b * 8; if (h > 8) h = 8;
            int cnt = (h * (h + 1)) / 2 + h * (NTILE - b * 8 - h);
            if (rem < cnt) break;
            rem -= cnt; b++;
        }
        const int base = b * 8;
        const int T = (h * (h + 1)) / 2;
        if (rem < T) {
            // triangle head: jt = base+k has k+1 entries (it = base..base+k)
            int k = 0, a2 = 0;
            while (a2 + k + 1 <= rem) { a2 += k + 1; k++; }
            jt_t = base + k;
            it_t = base + (rem - a2);
        } else {
            // rectangle: only bands with h==8 reach here -> /8 is a shift
            int r2 = rem - T;
            jt_t = base + h + (r2 >> 3);
            it_t = base + (r2 & 7);
        }
    }
    const int ib = it_t * TM, jb = jt_t * TM;

    // skip tiles that are entirely same-class
    {
        int ci0 = ib / CLS_P, ci1 = (ib + TM - 1) / CLS_P;
        int cj0 = jb / CLS_P, cj1 = (jb + TM - 1) / CLS_P;
        if (ci0 == ci1 && cj0 == cj1 && ci0 == cj0) return;
    }

    // 3 buffers x (A 8KB + B 8KB) = 48 KB
    __shared__ unsigned short S[3 * 8192];
    __shared__ int cred_i[TM], cred_j[TM];
    __shared__ int esc_n;
    __shared__ int2 esc_buf[ESC_LOC];

    const int tid = threadIdx.x;
    const int lane = tid & 63, w = tid >> 6;
    const int wi = (w & 1) * 64, wj = (w >> 1) * 64;
    const int quad = lane >> 4, col = lane & 15;

    if (tid == 0) esc_n = 0;

    // staging: waves 0,1 -> A (rows of ib); waves 2,3 -> B (rows of jb)
    const int warr = w >> 1;
    const int w01 = w & 1;
    const int rl0 = lane >> 2;      // 0..15 row within 16-row call group
    const int slot = lane & 3;      // dest k-slot
    const int q = (slot - rl0 - (rl0 >> 2)) & 3;   // source k-quarter (swizzle)
    const int rowbase = warr ? jb : ib;

    const unsigned short* src[4];
    #pragma unroll
    for (int b = 0; b < 4; b++) {
        int grow = rowbase + b * 32 + w01 * 16 + rl0;
        if (grow > N_TOT - 1) grow = N_TOT - 1;
        src[b] = Xh + (size_t)grow * D + q * 8;
    }

#define STAGE(KC_, BUFBASE_)                                                     \
    {                                                                            \
        _Pragma("unroll")                                                        \
        for (int b = 0; b < 4; b++) {                                            \
            __builtin_amdgcn_global_load_lds(                                    \
                (gptr_t)(src[b] + (KC_) * 32),                                   \
                (lptr_t)((BUFBASE_) + warr * 4096 + b * 1024 + w01 * 512),       \
                16, 0, 0);                                                       \
        }                                                                        \
    }

    // ---- hoisted frag LDS offsets (loop-invariant; shorts) ----
    int offA[4], offB[4];
    #pragma unroll
    for (int t = 0; t < 4; t++) {
        int rA = wi + t * 16 + col;
        offA[t] = rA * 32 + ((quad + rA + (rA >> 2)) & 3) * 8;
        int rB = wj + t * 16 + col;
        offB[t] = 4096 + rB * 32 + ((quad + rB + (rB >> 2)) & 3) * 8;
    }

#define FRAGS_(AH, BH, BUFBASE_)                                                 \
    {                                                                            \
        _Pragma("unroll")                                                        \
        for (int t = 0; t < 4; t++) {                                            \
            AH[t] = *(const f16x8*)((BUFBASE_) + offA[t]);                       \
            BH[t] = *(const f16x8*)((BUFBASE_) + offB[t]);                       \
        }                                                                        \
    }

#define MFMA16_(AH, BH)                                                          \
    {                                                                            \
        _Pragma("unroll")                                                        \
        for (int it = 0; it < 4; it++)                                           \
            _Pragma("unroll")                                                    \
            for (int jt = 0; jt < 4; jt++)                                       \
                acc[it][jt] = __builtin_amdgcn_mfma_f32_16x16x32_f16(AH[it], BH[jt], acc[it][jt], 0, 0, 0); \
    }

#define WAIT4_BAR asm volatile("s_waitcnt vmcnt(4)\ns_barrier" ::: "memory")
#define WAIT0_BAR asm volatile("s_waitcnt vmcnt(0)\ns_barrier" ::: "memory")

    f32x4 acc[4][4];
    #pragma unroll
    for (int it = 0; it < 4; it++)
        #pragma unroll
        for (int jt = 0; jt < 4; jt++)
            acc[it][jt] = (f32x4){0.f, 0.f, 0.f, 0.f};

    f16x8 ah0[4], bh0[4], ah1[4], bh1[4];   // two named frag sets (phase parity)

    unsigned short* p0 = S;                 // data kc   (cur, already in regs)
    unsigned short* p1 = S + 8192;          // data kc+1 (frags read this phase)
    unsigned short* p2 = S + 16384;         // free -> staging kc+2

    // prologue: stage kc0,kc1; retire kc0 (keep kc1 in flight); preload frags0
    STAGE(0, p0);
    STAGE(1, p1);
    WAIT4_BAR;
    FRAGS_(ah0, bh0, p0);

    for (int kc = 0; kc < KCHUNKS - 2; kc += 2) {
        // ---- phase m=kc (cur set0): stage kc+2, read-ahead frags kc+1 -> set1 ----
        STAGE(kc + 2, p2);
        WAIT4_BAR;                 // retire stage(kc+1) everywhere; gate p2 overwrite
        FRAGS_(ah1, bh1, p1);      // ds_reads overlap MFMA below
        MFMA16_(ah0, bh0);
        { unsigned short* t = p0; p0 = p1; p1 = p2; p2 = t; }

        // ---- phase m=kc+1 (cur set1): stage kc+3, read-ahead frags kc+2 -> set0 ----
        STAGE(kc + 3, p2);
        WAIT4_BAR;
        FRAGS_(ah0, bh0, p1);
        MFMA16_(ah1, bh1);
        { unsigned short* t = p0; p0 = p1; p1 = p2; p2 = t; }
    }
    // tail: phase 30 (cur set0), phase 31 (cur set1)
    WAIT0_BAR;                     // retire stage(31)
    FRAGS_(ah1, bh1, p1);
    MFMA16_(ah0, bh0);
    MFMA16_(ah1, bh1);

    // ---------------- epilogue: threshold + LDS-buffered escalate + symmetric reduce ----------------
    if (tid < TM) { cred_i[tid] = 0; cred_j[tid] = 0; }
    __syncthreads();

    const float thr_lo = 0.25f - DELTA;
    const float thr_hi = 0.25f + DELTA;
    const bool diag = (ib == jb);

    float sqj[4];
    int clsj[4], jv[4], jidx[4];
    #pragma unroll
    for (int jt = 0; jt < 4; jt++) {
        int j = jb + wj + jt * 16 + col;
        jidx[jt] = j;
        jv[jt] = (j < N_TOT);
        sqj[jt] = jv[jt] ? sqf[j] : 0.f;
        clsj[jt] = j / CLS_P;
    }

    int cj[4] = {0, 0, 0, 0};

    #pragma unroll
    for (int it = 0; it < 4; it++) {
        #pragma unroll
        for (int r = 0; r < 4; r++) {
            int irow = wi + it * 16 + quad * 4 + r;
            int i = ib + irow;
            bool iv = (i < N_TOT);
            float sqi = iv ? sqf[i] : 0.f;
            int clsi = i / CLS_P;
            int ci = 0;
            #pragma unroll
            for (int jt = 0; jt < 4; jt++) {
                int j = jidx[jt];
                bool ok = iv && jv[jt] && (clsj[jt] != clsi) && (!diag || j > i);
                float d2 = sqi + sqj[jt] - acc[it][jt][r] * INV_SCALE2;
                bool in = ok && (d2 < thr_lo);
                bool esc = ok && !in && (d2 < thr_hi);
                ci += in ? 1 : 0;
                cj[jt] += in ? 1 : 0;
                if (esc) {
                    int k = atomicAdd(&esc_n, 1);      // LDS atomic: fast
                    if (k < ESC_LOC) {
                        esc_buf[k] = make_int2(i, j);
                    } else {
                        // ~never (avg ~16/block, cap 256): exact inline scalar fp64 check
                        const float* xi = feats + (size_t)ids[i] * D;
                        const float* xj = feats + (size_t)ids[j] * D;
                        double s = 0.0;
                        for (int kk = 0; kk < D; kk++) s += (double)xi[kk] * xj[kk];
                        if (sqd[i] + sqd[j] - 2.0 * s < 0.25) {
                            atomicAdd(&counts[i], 1);
                            atomicAdd(&counts[j], 1);
                        }
                    }
                }
            }
            ci += __shfl_xor(ci, 1, 64);
            ci += __shfl_xor(ci, 2, 64);
            ci += __shfl_xor(ci, 4, 64);
            ci += __shfl_xor(ci, 8, 64);
            if (col == 0 && ci) atomicAdd(&cred_i[irow], ci);
        }
    }
    #pragma unroll
    for (int jt = 0; jt < 4; jt++) {
        int v = cj[jt];
        v += __shfl_xor(v, 16, 64);
        v += __shfl_xor(v, 32, 64);
        if (quad == 0 && v) atomicAdd(&cred_j[wj + jt * 16 + col], v);
    }
    __syncthreads();
    if (tid < TM) {
        int i = ib + tid;
        if (i < N_TOT && cred_i[tid]) atomicAdd(&counts[i], cred_i[tid]);
        int j = jb + tid;
        if (j < N_TOT && cred_j[tid]) atomicAdd(&counts[j], cred_j[tid]);
    }
    __syncthreads();   // esc_buf/esc_n visible to all waves

    // ---------------- fused fp64 escalation: 16 lanes/pair, 16 concurrent pairs ----------------
    int n = esc_n; if (n > ESC_LOC) n = ESC_LOC;
    const int sub = lane >> 4, l16 = lane & 15;
    for (int p = w * 4 + sub; p < n; p += 16) {
        int2 pr = esc_buf[p];
        const float* xi = feats + (size_t)ids[pr.x] * D;
        const float* xj = feats + (size_t)ids[pr.y] * D;
        double s = 0.0;
        int k0 = l16 * 64;
        #pragma unroll
        for (int k = 0; k < 64; k += 4) {
            float4 a = *(const float4*)(xi + k0 + k);
            float4 b = *(const float4*)(xj + k0 + k);
            s += (double)a.x * b.x + (double)a.y * b.y + (double)a.z * b.z + (double)a.w * b.w;
        }
        s += __shfl_xor(s, 1, 64);
        s += __shfl_xor(s, 2, 64);
        s += __shfl_xor(s, 4, 64);
        s += __shfl_xor(s, 8, 64);
        if (l16 == 0) {
            double d2 = sqd[pr.x] + sqd[pr.y] - 2.0 * s;
            if (d2 < 0.25) {
                atomicAdd(&counts[pr.x], 1);
                atomicAdd(&counts[pr.y], 1);
            }
        }
    }
}

// ---------------- stable-argsort selection (one thread per p) ----------------
__global__ void sel_kernel(const int* __restrict__ counts, const int* __restrict__ ids,
                           int* __restrict__ out_ids, int pcb) {
    int c = blockIdx.x;
    __shared__ int lc[CLS_P];
    for (int p = threadIdx.x; p < CLS_P; p += blockDim.x)
        lc[p] = counts[c * CLS_P + p];
    __syncthreads();
    int p = threadIdx.x;
    if (p < CLS_P) {
        int cp = lc[p];
        int rank = 0;
        for (int qq = 0; qq < CLS_P; qq++) {
            int cq = lc[qq];
            rank += (cq < cp) || (cq == cp && qq < p);
        }
        if (rank < pcb)
            out_ids[c * pcb + rank] = ids[c * CLS_P + p];
    }
}

extern "C" void kernel_launch(void* const* d_in, const int* in_sizes, int n_in,
                              void* d_out, int out_size, void* d_ws, size_t ws_size,
                              hipStream_t stream) {
    const float* feats = (const float*)d_in[0];
    const int* ids = (const int*)d_in[1];
    int budget = out_size - N_TOT;
    int pcb = budget / NC;  // 200
    int* out = (int*)d_out;
    int* counts_out = out + NC * pcb;

    char* ws = (char*)d_ws;
    const size_t XH_OFF = 0;
    const size_t SQD_OFF = XH_OFF + (size_t)N_TOT * D * 2;           // 20.48 MB
    const size_t SQF_OFF = SQD_OFF + (size_t)N_TOT * 8;

    unsigned short* Xh = (unsigned short*)(ws + XH_OFF);
    double* sqd = (double*)(ws + SQD_OFF);
    float* sqf = (float*)(ws + SQF_OFF);

    // counts zeroed inside prep; out_ids fully overwritten by sel (rank bijection)
    prep_kernel<<<N_TOT, 256, 0, stream>>>(feats, ids, Xh, sqd, sqf, counts_out);
    count_kernel<<<NACT, 256, 0, stream>>>(Xh, sqf, sqd, feats, ids, counts_out);
    sel_kernel<<<NC, 1024, 0, stream>>>(counts_out, ids, out, pcb);
}

// Round 9
// 321.440 us; speedup vs baseline: 1.1057x; 1.0206x over previous
//
#include <hip/hip_runtime.h>

#define N_TOT 10000
#define CLS_P 1000
#define NC 10
#define D 1024

#define TM 128            // block tile (i and j)
#define DELTA 1.35e-5f
#define INV_SCALE2 4.8828125e-4f   // 2 / 4096  (Xh stores 64*x; acc = 4096*dot)
#define ESC_LOC 256
#define KCHUNKS (D / 32)
#define NTILE ((N_TOT + TM - 1) / TM)   // 79
#define NACT ((NTILE * (NTILE + 1)) / 2)  // 3160 active (upper-tri) tiles
#define CHUNK (NACT / 8)                  // 395 (exact: 3160 = 8*395)

typedef _Float16 f16x8 __attribute__((ext_vector_type(8)));
typedef float f32x4 __attribute__((ext_vector_type(4)));
typedef const __attribute__((address_space(1))) unsigned int* gptr_t;
typedef __attribute__((address_space(3))) unsigned int* lptr_t;

// ---------------- gather + fp16(64x) + fp64 norms + fused counts-zero ----------------
// One WAVE per row (4 rows / 256-thr block, 2500 blocks): no LDS, no
// __syncthreads, pure shfl reduce -- removes the per-row block-dispatch + sync
// overhead of the previous 10000-block version.  fp64 sum order changes only
// (~1e-16 rel); borderline pairs sit inside the escalation band either way.
__global__ void prep_kernel(const float* __restrict__ feats, const int* __restrict__ ids,
                            unsigned short* __restrict__ Xh,
                            double* __restrict__ sqd, float* __restrict__ sqf,
                            int* __restrict__ counts) {
    const int wv = threadIdx.x >> 6;        // 0..3
    const int lane = threadIdx.x & 63;
    const int row = blockIdx.x * 4 + wv;    // 2500 * 4 = 10000 exactly
    const int id = ids[row];
    const float4* rp = (const float4*)(feats + (size_t)id * D);
    ushort4* op = (ushort4*)(Xh + (size_t)row * D);
    double s = 0.0;
    #pragma unroll
    for (int it = 0; it < 4; it++) {
        float4 v = rp[it * 64 + lane];      // coalesced: 64 lanes x 16B
        float f[4] = {v.x, v.y, v.z, v.w};
        ushort4 hv;
        unsigned short* hp = &hv.x;
        #pragma unroll
        for (int e = 0; e < 4; e++) {
            s += (double)f[e] * f[e];
            union { _Float16 h; unsigned short u; } cv;
            cv.h = (_Float16)(f[e] * 64.0f);   // RNE; x64 avoids fp16 denormals
            hp[e] = cv.u;
        }
        op[it * 64 + lane] = hv;
    }
    #pragma unroll
    for (int off = 32; off > 0; off >>= 1)
        s += __shfl_down(s, off, 64);
    if (lane == 0) {
        sqd[row] = s;
        sqf[row] = (float)s;
        counts[row] = 0;        // fused zero (stream-ordered before count_kernel)
    }
}

// ---------------- fp16 MFMA pairwise count (3-buf async, frag read-ahead, fused fp64 escalation) ----------------
// FINAL (R6-verified, ~220 us count): balanced active-tile XCD chunking
// (3160 = 8*395 upper-tri tiles, band-major j-fastest -> per-XCD L2-resident
// A-band, FETCH 452->224 MB, zero tail imbalance) + ring-3 LDS with counted
// vmcnt(4) and cross-chunk fragment read-ahead (16x16x32 MFMA, 16 independent
// MFMAs/cluster feeds the 3-wave/SIMD interleave).
// Bracketing measured this session: 8-phase/counted-vmcnt/sched_barrier
// schedules (R1-R3) worse at 1 block/CU; ring-2 4-block (R4, 37.9% occ) 250us;
// 32x32x16 shape (R7) 270us despite zero bank conflicts.
__launch_bounds__(256, 3)
__global__ void count_kernel(const unsigned short* __restrict__ Xh,
                             const float* __restrict__ sqf,
                             const double* __restrict__ sqd,
                             const float* __restrict__ feats,
                             const int* __restrict__ ids,
                             int* __restrict__ counts) {
    // ---- XCD chunk remap (3160 = 8*395 exactly -> bijective) ----
    const int hw = blockIdx.x;
    const int gid = (hw & 7) * CHUNK + (hw >> 3);

    // ---- balanced active-tile decode: band-major (8 i-tiles/band), j-fastest ----
    int it_t, jt_t;
    {
        int rem = gid, b = 0, h;
        while (true) {
            h = NTILE - b * 8; if (h > 8) h = 8;
            int cnt = (h * (h + 1)) / 2 + h * (NTILE - b * 8 - h);
            if (rem < cnt) break;
            rem -= cnt; b++;
        }
        const int base = b * 8;
        const int T = (h * (h + 1)) / 2;
        if (rem < T) {
            // triangle head: jt = base+k has k+1 entries (it = base..base+k)
            int k = 0, a2 = 0;
            while (a2 + k + 1 <= rem) { a2 += k + 1; k++; }
            jt_t = base + k;
            it_t = base + (rem - a2);
        } else {
            // rectangle: only bands with h==8 reach here -> /8 is a shift
            int r2 = rem - T;
            jt_t = base + h + (r2 >> 3);
            it_t = base + (r2 & 7);
        }
    }
    const int ib = it_t * TM, jb = jt_t * TM;

    // skip tiles that are entirely same-class
    {
        int ci0 = ib / CLS_P, ci1 = (ib + TM - 1) / CLS_P;
        int cj0 = jb / CLS_P, cj1 = (jb + TM - 1) / CLS_P;
        if (ci0 == ci1 && cj0 == cj1 && ci0 == cj0) return;
    }

    // 3 buffers x (A 8KB + B 8KB) = 48 KB
    __shared__ unsigned short S[3 * 8192];
    __shared__ int cred_i[TM], cred_j[TM];
    __shared__ int esc_n;
    __shared__ int2 esc_buf[ESC_LOC];

    const int tid = threadIdx.x;
    const int lane = tid & 63, w = tid >> 6;
    const int wi = (w & 1) * 64, wj = (w >> 1) * 64;
    const int quad = lane >> 4, col = lane & 15;

    if (tid == 0) esc_n = 0;

    // staging: waves 0,1 -> A (rows of ib); waves 2,3 -> B (rows of jb)
    const int warr = w >> 1;
    const int w01 = w & 1;
    const int rl0 = lane >> 2;      // 0..15 row within 16-row call group
    const int slot = lane & 3;      // dest k-slot
    const int q = (slot - rl0 - (rl0 >> 2)) & 3;   // source k-quarter (swizzle)
    const int rowbase = warr ? jb : ib;

    const unsigned short* src[4];
    #pragma unroll
    for (int b = 0; b < 4; b++) {
        int grow = rowbase + b * 32 + w01 * 16 + rl0;
        if (grow > N_TOT - 1) grow = N_TOT - 1;
        src[b] = Xh + (size_t)grow * D + q * 8;
    }

#define STAGE(KC_, BUFBASE_)                                                     \
    {                                                                            \
        _Pragma("unroll")                                                        \
        for (int b = 0; b < 4; b++) {                                            \
            __builtin_amdgcn_global_load_lds(                                    \
                (gptr_t)(src[b] + (KC_) * 32),                                   \
                (lptr_t)((BUFBASE_) + warr * 4096 + b * 1024 + w01 * 512),       \
                16, 0, 0);                                                       \
        }                                                                        \
    }

    // ---- hoisted frag LDS offsets (loop-invariant; shorts) ----
    int offA[4], offB[4];
    #pragma unroll
    for (int t = 0; t < 4; t++) {
        int rA = wi + t * 16 + col;
        offA[t] = rA * 32 + ((quad + rA + (rA >> 2)) & 3) * 8;
        int rB = wj + t * 16 + col;
        offB[t] = 4096 + rB * 32 + ((quad + rB + (rB >> 2)) & 3) * 8;
    }

#define FRAGS_(AH, BH, BUFBASE_)                                                 \
    {                                                                            \
        _Pragma("unroll")                                                        \
        for (int t = 0; t < 4; t++) {                                            \
            AH[t] = *(const f16x8*)((BUFBASE_) + offA[t]);                       \
            BH[t] = *(const f16x8*)((BUFBASE_) + offB[t]);                       \
        }                                                                        \
    }

#define MFMA16_(AH, BH)                                                          \
    {                                                                            \
        _Pragma("unroll")                                                        \
        for (int it = 0; it < 4; it++)                                           \
            _Pragma("unroll")                                                    \
            for (int jt = 0; jt < 4; jt++)                                       \
                acc[it][jt] = __builtin_amdgcn_mfma_f32_16x16x32_f16(AH[it], BH[jt], acc[it][jt], 0, 0, 0); \
    }

#define WAIT4_BAR asm volatile("s_waitcnt vmcnt(4)\ns_barrier" ::: "memory")
#define WAIT0_BAR asm volatile("s_waitcnt vmcnt(0)\ns_barrier" ::: "memory")

    f32x4 acc[4][4];
    #pragma unroll
    for (int it = 0; it < 4; it++)
        #pragma unroll
        for (int jt = 0; jt < 4; jt++)
            acc[it][jt] = (f32x4){0.f, 0.f, 0.f, 0.f};

    f16x8 ah0[4], bh0[4], ah1[4], bh1[4];   // two named frag sets (phase parity)

    unsigned short* p0 = S;                 // data kc   (cur, already in regs)
    unsigned short* p1 = S + 8192;          // data kc+1 (frags read this phase)
    unsigned short* p2 = S + 16384;         // free -> staging kc+2

    // prologue: stage kc0,kc1; retire kc0 (keep kc1 in flight); preload frags0
    STAGE(0, p0);
    STAGE(1, p1);
    WAIT4_BAR;
    FRAGS_(ah0, bh0, p0);

    for (int kc = 0; kc < KCHUNKS - 2; kc += 2) {
        // ---- phase m=kc (cur set0): stage kc+2, read-ahead frags kc+1 -> set1 ----
        STAGE(kc + 2, p2);
        WAIT4_BAR;                 // retire stage(kc+1) everywhere; gate p2 overwrite
        FRAGS_(ah1, bh1, p1);      // ds_reads overlap MFMA below
        MFMA16_(ah0, bh0);
        { unsigned short* t = p0; p0 = p1; p1 = p2; p2 = t; }

        // ---- phase m=kc+1 (cur set1): stage kc+3, read-ahead frags kc+2 -> set0 ----
        STAGE(kc + 3, p2);
        WAIT4_BAR;
        FRAGS_(ah0, bh0, p1);
        MFMA16_(ah1, bh1);
        { unsigned short* t = p0; p0 = p1; p1 = p2; p2 = t; }
    }
    // tail: phase 30 (cur set0), phase 31 (cur set1)
    WAIT0_BAR;                     // retire stage(31)
    FRAGS_(ah1, bh1, p1);
    MFMA16_(ah0, bh0);
    MFMA16_(ah1, bh1);

    // ---------------- epilogue: threshold + LDS-buffered escalate + symmetric reduce ----------------
    if (tid < TM) { cred_i[tid] = 0; cred_j[tid] = 0; }
    __syncthreads();

    const float thr_lo = 0.25f - DELTA;
    const float thr_hi = 0.25f + DELTA;
    const bool diag = (ib == jb);

    float sqj[4];
    int clsj[4], jv[4], jidx[4];
    #pragma unroll
    for (int jt = 0; jt < 4; jt++) {
        int j = jb + wj + jt * 16 + col;
        jidx[jt] = j;
        jv[jt] = (j < N_TOT);
        sqj[jt] = jv[jt] ? sqf[j] : 0.f;
        clsj[jt] = j / CLS_P;
    }

    int cj[4] = {0, 0, 0, 0};

    #pragma unroll
    for (int it = 0; it < 4; it++) {
        #pragma unroll
        for (int r = 0; r < 4; r++) {
            int irow = wi + it * 16 + quad * 4 + r;
            int i = ib + irow;
            bool iv = (i < N_TOT);
            float sqi = iv ? sqf[i] : 0.f;
            int clsi = i / CLS_P;
            int ci = 0;
            #pragma unroll
            for (int jt = 0; jt < 4; jt++) {
                int j = jidx[jt];
                bool ok = iv && jv[jt] && (clsj[jt] != clsi) && (!diag || j > i);
                float d2 = sqi + sqj[jt] - acc[it][jt][r] * INV_SCALE2;
                bool in = ok && (d2 < thr_lo);
                bool esc = ok && !in && (d2 < thr_hi);
                ci += in ? 1 : 0;
                cj[jt] += in ? 1 : 0;
                if (esc) {
                    int k = atomicAdd(&esc_n, 1);      // LDS atomic: fast
                    if (k < ESC_LOC) {
                        esc_buf[k] = make_int2(i, j);
                    } else {
                        // ~never (avg ~16/block, cap 256): exact inline scalar fp64 check
                        const float* xi = feats + (size_t)ids[i] * D;
                        const float* xj = feats + (size_t)ids[j] * D;
                        double s = 0.0;
                        for (int kk = 0; kk < D; kk++) s += (double)xi[kk] * xj[kk];
                        if (sqd[i] + sqd[j] - 2.0 * s < 0.25) {
                            atomicAdd(&counts[i], 1);
                            atomicAdd(&counts[j], 1);
                        }
                    }
                }
            }
            ci += __shfl_xor(ci, 1, 64);
            ci += __shfl_xor(ci, 2, 64);
            ci += __shfl_xor(ci, 4, 64);
            ci += __shfl_xor(ci, 8, 64);
            if (col == 0 && ci) atomicAdd(&cred_i[irow], ci);
        }
    }
    #pragma unroll
    for (int jt = 0; jt < 4; jt++) {
        int v = cj[jt];
        v += __shfl_xor(v, 16, 64);
        v += __shfl_xor(v, 32, 64);
        if (quad == 0 && v) atomicAdd(&cred_j[wj + jt * 16 + col], v);
    }
    __syncthreads();
    if (tid < TM) {
        int i = ib + tid;
        if (i < N_TOT && cred_i[tid]) atomicAdd(&counts[i], cred_i[tid]);
        int j = jb + tid;
        if (j < N_TOT && cred_j[tid]) atomicAdd(&counts[j], cred_j[tid]);
    }
    __syncthreads();   // esc_buf/esc_n visible to all waves

    // ---------------- fused fp64 escalation: 16 lanes/pair, 16 concurrent pairs ----------------
    int n = esc_n; if (n > ESC_LOC) n = ESC_LOC;
    const int sub = lane >> 4, l16 = lane & 15;
    for (int p = w * 4 + sub; p < n; p += 16) {
        int2 pr = esc_buf[p];
        const float* xi = feats + (size_t)ids[pr.x] * D;
        const float* xj = feats + (size_t)ids[pr.y] * D;
        double s = 0.0;
        int k0 = l16 * 64;
        #pragma unroll
        for (int k = 0; k < 64; k += 4) {
            float4 a = *(const float4*)(xi + k0 + k);
            float4 b = *(const float4*)(xj + k0 + k);
            s += (double)a.x * b.x + (double)a.y * b.y + (double)a.z * b.z + (double)a.w * b.w;
        }
        s += __shfl_xor(s, 1, 64);
        s += __shfl_xor(s, 2, 64);
        s += __shfl_xor(s, 4, 64);
        s += __shfl_xor(s, 8, 64);
        if (l16 == 0) {
            double d2 = sqd[pr.x] + sqd[pr.y] - 2.0 * s;
            if (d2 < 0.25) {
                atomicAdd(&counts[pr.x], 1);
                atomicAdd(&counts[pr.y], 1);
            }
        }
    }
}

// ---------------- stable-argsort selection (one thread per p) ----------------
__global__ void sel_kernel(const int* __restrict__ counts, const int* __restrict__ ids,
                           int* __restrict__ out_ids, int pcb) {
    int c = blockIdx.x;
    __shared__ int lc[CLS_P];
    for (int p = threadIdx.x; p < CLS_P; p += blockDim.x)
        lc[p] = counts[c * CLS_P + p];
    __syncthreads();
    int p = threadIdx.x;
    if (p < CLS_P) {
        int cp = lc[p];
        int rank = 0;
        for (int qq = 0; qq < CLS_P; qq++) {
            int cq = lc[qq];
            rank += (cq < cp) || (cq == cp && qq < p);
        }
        if (rank < pcb)
            out_ids[c * pcb + rank] = ids[c * CLS_P + p];
    }
}

extern "C" void kernel_launch(void* const* d_in, const int* in_sizes, int n_in,
                              void* d_out, int out_size, void* d_ws, size_t ws_size,
                              hipStream_t stream) {
    const float* feats = (const float*)d_in[0];
    const int* ids = (const int*)d_in[1];
    int budget = out_size - N_TOT;
    int pcb = budget / NC;  // 200
    int* out = (int*)d_out;
    int* counts_out = out + NC * pcb;

    char* ws = (char*)d_ws;
    const size_t XH_OFF = 0;
    const size_t SQD_OFF = XH_OFF + (size_t)N_TOT * D * 2;           // 20.48 MB
    const size_t SQF_OFF = SQD_OFF + (size_t)N_TOT * 8;

    unsigned short* Xh = (unsigned short*)(ws + XH_OFF);
    double* sqd = (double*)(ws + SQD_OFF);
    float* sqf = (float*)(ws + SQF_OFF);

    // counts zeroed inside prep; out_ids fully overwritten by sel (rank bijection)
    prep_kernel<<<N_TOT / 4, 256, 0, stream>>>(feats, ids, Xh, sqd, sqf, counts_out);
    count_kernel<<<NACT, 256, 0, stream>>>(Xh, sqf, sqd, feats, ids, counts_out);
    sel_kernel<<<NC, 1024, 0, stream>>>(counts_out, ids, out, pcb);
}